// Round 15
// baseline (197.711 us; speedup 1.0000x reference)
//
#include <hip/hip_runtime.h>
#include <hip/hip_bf16.h>

#define BB 4
#define TT 2048
#define DD 1024
#define HH 16
#define HDIM 64
#define BT (BB*TT)       // 8192
#define D3 (3*DD)        // 3072

typedef __attribute__((ext_vector_type(8))) short bf16x8;
typedef __attribute__((ext_vector_type(4))) float f32x4;

#if __has_builtin(__builtin_amdgcn_exp2f)
#define EXP2(x) __builtin_amdgcn_exp2f(x)
#else
#define EXP2(x) exp2f(x)
#endif

__device__ __forceinline__ ushort f2bf(float f) {
  union { float f; uint32_t u; } v; v.f = f;
  uint32_t u = v.u + 0x7FFFu + ((v.u >> 16) & 1u);
  return (ushort)(u >> 16);
}

__device__ __forceinline__ ushort f2bf_hw(float f) {
  __hip_bfloat16 h = __float2bfloat16(f);
  ushort u;
  __builtin_memcpy(&u, &h, 2);
  return u;
}

__device__ __forceinline__ float bf2f(ushort u) {
  union { uint32_t i; float f; } x; x.i = ((uint32_t)u) << 16; return x.f;
}

__device__ __forceinline__ void gload_lds16(const void* g, void* l) {
  __builtin_amdgcn_global_load_lds((const __attribute__((address_space(1))) void*)g,
                                   (__attribute__((address_space(3))) void*)l, 16, 0, 0);
}

// ---------------- fp32 -> bf16 convert (+ work-queue ctr zero) ----------------
__global__ __launch_bounds__(256)
void cvt_bf16(const float* __restrict__ in, ushort* __restrict__ out, int n4,
              uint* __restrict__ ctr) {
  if (blockIdx.x == 0 && threadIdx.x == 0) *ctr = 0u;
  int i = blockIdx.x * blockDim.x + threadIdx.x;
  int stride = gridDim.x * blockDim.x;
  for (; i < n4; i += stride) {
    float4 v = ((const float4*)in)[i];
    ushort4 o;
    o.x = f2bf(v.x); o.y = f2bf(v.y); o.z = f2bf(v.z); o.w = f2bf(v.w);
    ((ushort4*)out)[i] = o;
  }
}

// ---------------- fp32 [K][N] -> bf16 transposed [N][K] ----------------
__global__ __launch_bounds__(256)
void transpose_cvt(const float* __restrict__ W, ushort* __restrict__ Wt, int K, int N) {
  __shared__ ushort Tt[64][68];
  const int n0 = blockIdx.x * 64;
  const int k0 = blockIdx.y * 64;
  const int tid = threadIdx.x;
  const int r = tid >> 4;
  const int c4 = (tid & 15) * 4;
  #pragma unroll
  for (int i = 0; i < 4; ++i) {
    int row = r + i * 16;   // k-local
    float4 v = *(const float4*)&W[(size_t)(k0 + row) * N + n0 + c4];
    Tt[c4 + 0][row] = f2bf(v.x);
    Tt[c4 + 1][row] = f2bf(v.y);
    Tt[c4 + 2][row] = f2bf(v.z);
    Tt[c4 + 3][row] = f2bf(v.w);
  }
  __syncthreads();
  #pragma unroll
  for (int i = 0; i < 4; ++i) {
    int row = r + i * 16;   // n-local
    ushort4 tv = *(const ushort4*)&Tt[row][c4];
    *(ushort4*)&Wt[(size_t)(n0 + row) * K + k0 + c4] = tv;
  }
}

// ---------------- 128x256 phased bf16 GEMM (8-wave, dbuf LDS) ----------------
template<bool F32OUT>
__global__ __launch_bounds__(512, 2)
void gemm_8p(const ushort* __restrict__ A, const ushort* __restrict__ Bw,
             const float* __restrict__ bias, void* __restrict__ C, int N) {
  __shared__ __align__(16) short lds[2 * (128 + 256) * 64];   // 96 KB

  const int tid = threadIdx.x;
  const int w = tid >> 6;          // 0..7
  const int wm = w >> 2;           // 0..1
  const int wn = w & 3;            // 0..3
  const int lane = tid & 63;
  const int li = lane & 15, g = lane >> 4;
  const int swz = (li & 7) << 4;   // read-side XOR (16B slot spread)

  const int bm = blockIdx.y * 128;
  const int bn = blockIdx.x * 256;
  const ushort* Ag = A + (size_t)bm * 1024;
  const ushort* Bg = Bw + (size_t)bn * 1024;

  const int lrow8 = lane >> 3;           // 0..7 (row within 8-row wave slab)
  const int chsw = (lane & 7) ^ lrow8;   // source chunk pre-swizzle (rule 21)

  f32x4 acc[4][4] = {};

#define STAGE6(t, p) do { \
  const int kk_ = (t) * 64; \
  short* Ad_ = lds + (p) * 24576; \
  short* Bd_ = Ad_ + 8192; \
  _Pragma("unroll") \
  for (int h_ = 0; h_ < 2; ++h_) { \
    const int r_ = h_ * 64 + w * 8; \
    gload_lds16(Ag + (size_t)(r_ + lrow8) * 1024 + kk_ + chsw * 8, Ad_ + r_ * 64); \
  } \
  _Pragma("unroll") \
  for (int j_ = 0; j_ < 4; ++j_) { \
    const int r_ = j_ * 64 + w * 8; \
    gload_lds16(Bg + (size_t)(r_ + lrow8) * 1024 + kk_ + chsw * 8, Bd_ + r_ * 64); \
  } \
} while (0)

  STAGE6(0, 0);
  asm volatile("s_waitcnt vmcnt(0)" ::: "memory");
  __builtin_amdgcn_sched_barrier(0);
  __builtin_amdgcn_s_barrier();

  for (int s = 0; s < 16; ++s) {
    const int cur = s & 1;
    const char* Ab = (const char*)lds + cur * 49152;   // bytes
    const char* Bb = Ab + 16384;

    if (s + 1 < 16) STAGE6(s + 1, cur ^ 1);

    #pragma unroll
    for (int kh = 0; kh < 2; ++kh) {
      bf16x8 af[4], bf[4];
      #pragma unroll
      for (int mi = 0; mi < 4; ++mi)
        af[mi] = *(const bf16x8*)(Ab + (wm * 64 + mi * 16 + li) * 128 + ((kh * 64 + g * 16) ^ swz));
      #pragma unroll
      for (int ni = 0; ni < 4; ++ni)
        bf[ni] = *(const bf16x8*)(Bb + (wn * 64 + ni * 16 + li) * 128 + ((kh * 64 + g * 16) ^ swz));
      __builtin_amdgcn_s_setprio(1);
      #pragma unroll
      for (int mi = 0; mi < 4; ++mi)
        #pragma unroll
        for (int ni = 0; ni < 4; ++ni)
          acc[mi][ni] = __builtin_amdgcn_mfma_f32_16x16x32_bf16(af[mi], bf[ni], acc[mi][ni], 0, 0, 0);
      __builtin_amdgcn_s_setprio(0);
      if (kh == 0) __builtin_amdgcn_s_barrier();
    }
    // ---- K-step boundary: next tile's loads must be in LDS ----
    asm volatile("s_waitcnt vmcnt(0)" ::: "memory");
    __builtin_amdgcn_sched_barrier(0);
    __builtin_amdgcn_s_barrier();
  }
#undef STAGE6

  #pragma unroll
  for (int ni = 0; ni < 4; ++ni) {
    int col = bn + wn * 64 + ni * 16 + li;
    float bv = bias[col];
    #pragma unroll
    for (int mi = 0; mi < 4; ++mi) {
      int row = bm + wm * 64 + mi * 16 + g * 4;
      #pragma unroll
      for (int r = 0; r < 4; ++r) {
        float v = acc[mi][ni][r] + bv;
        if (F32OUT) ((float*)C)[(size_t)(row + r) * N + col] = v;
        else        ((ushort*)C)[(size_t)(row + r) * N + col] = f2bf_hw(v);
      }
    }
  }
}

// ---------------- MFMA flash attention (persistent queue, 128-key windows) ----------------
// R9-proven sync template; per barrier window now covers 128 keys, processed as
// two 64-key chunks (each chunk = the verified compute body, register/LDS-read
// only). Halves barriers/commits/prefetch-issues per key. LDS 40KB -> 4 blk/CU.
#define NITEMS 1024

__global__ __launch_bounds__(256)
void attn_mfma(const ushort* __restrict__ qkv, ushort* __restrict__ out,
               uint* __restrict__ ctr) {
  __shared__ __align__(16) short Ks[128 * 64];    // 128 keys x 128B
  __shared__ __align__(16) short Vt[64 * 128];    // 64 d x 256B (128 keys)
  __shared__ __align__(16) short Pl[4 * 16 * 64]; // per-wave P (64-key chunk, reused)
  __shared__ int s_item;

  const int tid = threadIdx.x;
  const int w = tid >> 6;
  const int lane = tid & 63;
  const int li = lane & 15, g = lane >> 4;
  const int sw = (li & 7) << 4;     // XOR swizzle const for this lane's rows

  char* KsB = (char*)Ks;
  char* VtB = (char*)Vt;
  char* PlB = (char*)Pl + w * 2048;

  const int krow0 = tid >> 3;     // 0..31
  const int kc = tid & 7;
  const int d0 = (tid >> 5) * 8;
  const int kp = tid & 31;        // V: keys 4*kp .. 4*kp+3
  const int kswz = (kc * 16) ^ ((krow0 & 7) << 4);

  for (;;) {
    if (tid == 0) s_item = (int)atomicAdd(ctr, 1u);
    __syncthreads();
    const int item = s_item;
    if (item >= NITEMS) return;

    const int qt = 15 - (item >> 6);   // longest first
    const int bh = item & 63;
    const int h = bh & 15, b = bh >> 4;
    const int qg0 = qt * 128 + w * 32;

    // Q frags, scaled by 1/sqrt(64) * log2(e)
    bf16x8 qfr[2][2];
    #pragma unroll
    for (int qf = 0; qf < 2; ++qf) {
      const ushort* qrow = qkv + (size_t)(b * TT + qg0 + qf * 16 + li) * D3 + h * HDIM;
      #pragma unroll
      for (int c = 0; c < 2; ++c) {
        uint4 raw = *(const uint4*)(qrow + c * 32 + g * 8);
        const ushort* rp = (const ushort*)&raw;
        bf16x8 v;
        #pragma unroll
        for (int j = 0; j < 8; ++j)
          v[j] = (short)f2bf_hw(bf2f(rp[j]) * 0.18033688f);
        qfr[qf][c] = v;
      }
    }

    f32x4 o[4][2] = {};
    float lsum[2] = {0.f, 0.f};

    const ushort* kbase = qkv + (size_t)b * TT * D3 + DD + h * HDIM;
    const ushort* vbase = kbase + DD;

    const int nIter = qt + 1;                 // 128-key windows
    const int itlast = 2 * qt + (w >> 1);     // in 64-key-tile units

    uint4 kpre[4], vpre[4];
    {
      const ushort* kg = kbase + (size_t)krow0 * D3 + kc * 8;
      #pragma unroll
      for (int i = 0; i < 4; ++i)
        kpre[i] = *(const uint4*)(kg + (size_t)(32 * i) * D3);
      const ushort* vg = vbase + (size_t)(4 * kp) * D3 + d0;
      #pragma unroll
      for (int j = 0; j < 4; ++j)
        vpre[j] = *(const uint4*)(vg + (size_t)j * D3);
    }

    for (int it = 0; it < nIter; ++it) {
      // commit prefetched 128-key tile to LDS (swizzled rows)
      #pragma unroll
      for (int i = 0; i < 4; ++i)
        *(uint4*)(KsB + (krow0 + 32 * i) * 128 + kswz) = kpre[i];
      {
        const ushort* p0 = (const ushort*)&vpre[0];
        const ushort* p1 = (const ushort*)&vpre[1];
        const ushort* p2 = (const ushort*)&vpre[2];
        const ushort* p3 = (const ushort*)&vpre[3];
        #pragma unroll
        for (int j = 0; j < 8; ++j) {
          uint32_t lo = (uint32_t)p0[j] | ((uint32_t)p1[j] << 16);
          uint32_t hi = (uint32_t)p2[j] | ((uint32_t)p3[j] << 16);
          *(uint32_t*)(VtB + (d0 + j) * 256 + ((8 * kp) ^ (j << 4))) = lo;
          *(uint32_t*)(VtB + (d0 + j) * 256 + ((8 * kp + 4) ^ (j << 4))) = hi;
        }
      }
      __syncthreads();
      // prefetch next 128-key tile (overlaps compute)
      if (it + 1 < nIter) {
        const ushort* kg = kbase + (size_t)((it + 1) * 128 + krow0) * D3 + kc * 8;
        #pragma unroll
        for (int i = 0; i < 4; ++i)
          kpre[i] = *(const uint4*)(kg + (size_t)(32 * i) * D3);
        const ushort* vg = vbase + (size_t)((it + 1) * 128 + 4 * kp) * D3 + d0;
        #pragma unroll
        for (int j = 0; j < 4; ++j)
          vpre[j] = *(const uint4*)(vg + (size_t)j * D3);
      }
      // two 64-key chunks inside one barrier window
      #pragma unroll
      for (int c = 0; c < 2; ++c) {
        const int t = 2 * it + c;
        if (t <= itlast) {
          const bool domask = (t == itlast);
          const int k0 = t * 64;
          bf16x8 pf[2][2];
          f32x4 s[2][4];
          // QK^T: K frags loaded once, used by both q-frags
          __builtin_amdgcn_s_setprio(1);
          #pragma unroll
          for (int kt = 0; kt < 4; ++kt) {
            const int row = c * 64 + kt * 16 + li;
            bf16x8 kf0 = *(bf16x8*)(KsB + row * 128 + ((g * 16) ^ sw));
            bf16x8 kf1 = *(bf16x8*)(KsB + row * 128 + ((64 + g * 16) ^ sw));
            #pragma unroll
            for (int qf = 0; qf < 2; ++qf) {
              f32x4 a = {0.f, 0.f, 0.f, 0.f};
              a = __builtin_amdgcn_mfma_f32_16x16x32_bf16(kf0, qfr[qf][0], a, 0, 0, 0);
              a = __builtin_amdgcn_mfma_f32_16x16x32_bf16(kf1, qfr[qf][1], a, 0, 0, 0);
              s[qf][kt] = a;
            }
          }
          __builtin_amdgcn_s_setprio(0);
          // softmax numerator: P = exp2(s) directly (|s| < ~12 in log2 domain)
          #pragma unroll
          for (int qf = 0; qf < 2; ++qf) {
            const int qrow = qg0 + qf * 16 + li;
            if (domask) {
              #pragma unroll
              for (int kt = 0; kt < 4; ++kt)
                #pragma unroll
                for (int r = 0; r < 4; ++r) {
                  int key = k0 + kt * 16 + g * 4 + r;
                  if (key > qrow) s[qf][kt][r] = -1e30f;
                }
            }
            float ls = 0.f;
            #pragma unroll
            for (int kt = 0; kt < 4; ++kt) {
              float p0 = EXP2(s[qf][kt][0]);
              float p1 = EXP2(s[qf][kt][1]);
              float p2 = EXP2(s[qf][kt][2]);
              float p3 = EXP2(s[qf][kt][3]);
              ls += (p0 + p1) + (p2 + p3);
              uint2 val;
              val.x = (uint32_t)f2bf_hw(p0) | ((uint32_t)f2bf_hw(p1) << 16);
              val.y = (uint32_t)f2bf_hw(p2) | ((uint32_t)f2bf_hw(p3) << 16);
              *(uint2*)(PlB + li * 128 + ((kt * 32 + g * 8) ^ sw)) = val;
            }
            lsum[qf] += ls;
            pf[qf][0] = *(bf16x8*)(PlB + li * 128 + ((g * 16) ^ sw));
            pf[qf][1] = *(bf16x8*)(PlB + li * 128 + ((64 + g * 16) ^ sw));
          }
          __builtin_amdgcn_s_setprio(1);
          #pragma unroll
          for (int dt = 0; dt < 4; ++dt) {
            const int vrow = dt * 16 + li;
            bf16x8 vf0 = *(bf16x8*)(VtB + vrow * 256 + ((c * 128 + g * 16) ^ sw));
            bf16x8 vf1 = *(bf16x8*)(VtB + vrow * 256 + ((c * 128 + 64 + g * 16) ^ sw));
            #pragma unroll
            for (int qf = 0; qf < 2; ++qf) {
              o[dt][qf] = __builtin_amdgcn_mfma_f32_16x16x32_bf16(vf0, pf[qf][0], o[dt][qf], 0, 0, 0);
              o[dt][qf] = __builtin_amdgcn_mfma_f32_16x16x32_bf16(vf1, pf[qf][1], o[dt][qf], 0, 0, 0);
            }
          }
          __builtin_amdgcn_s_setprio(0);
        }
      }
      __syncthreads();
    }

    #pragma unroll
    for (int qf = 0; qf < 2; ++qf) {
      float lt = lsum[qf];
      lt += __shfl_xor(lt, 16);
      lt += __shfl_xor(lt, 32);
      float inv = 1.f / lt;
      ushort* orow = out + (size_t)(b * TT + qg0 + qf * 16 + li) * DD + h * HDIM;
      #pragma unroll
      for (int dt = 0; dt < 4; ++dt) {
        uint2 pk;
        pk.x = (uint32_t)f2bf_hw(o[dt][qf][0] * inv) | ((uint32_t)f2bf_hw(o[dt][qf][1] * inv) << 16);
        pk.y = (uint32_t)f2bf_hw(o[dt][qf][2] * inv) | ((uint32_t)f2bf_hw(o[dt][qf][3] * inv) << 16);
        *(uint2*)&orow[dt * 16 + g * 4] = pk;
      }
    }
  }
}

extern "C" void kernel_launch(void* const* d_in, const int* in_sizes, int n_in,
                              void* d_out, int out_size, void* d_ws, size_t ws_size,
                              hipStream_t stream) {
  const float* x     = (const float*)d_in[0];
  const float* W_qkv = (const float*)d_in[1];
  const float* b_qkv = (const float*)d_in[2];
  const float* W_out = (const float*)d_in[3];
  const float* b_out = (const float*)d_in[4];
  float* out = (float*)d_out;

  ushort* x_bf   = (ushort*)d_ws;                   // 8192*1024
  ushort* wtq    = x_bf + (size_t)BT * DD;          // 3072*1024
  ushort* wto    = wtq + (size_t)D3 * DD;           // 1024*1024
  ushort* qkv_bf = wto + (size_t)DD * DD;           // 8192*3072
  ushort* att_bf = qkv_bf + (size_t)BT * D3;        // 8192*1024
  uint*   ctr    = (uint*)(att_bf + (size_t)BT * DD);

  cvt_bf16<<<2048, 256, 0, stream>>>(x, x_bf, BT * DD / 4, ctr);
  transpose_cvt<<<dim3(D3 / 64, DD / 64), 256, 0, stream>>>(W_qkv, wtq, DD, D3);
  transpose_cvt<<<dim3(DD / 64, DD / 64), 256, 0, stream>>>(W_out, wto, DD, DD);

  gemm_8p<false><<<dim3(D3 / 256, BT / 128), 512, 0, stream>>>(x_bf, wtq, b_qkv, (void*)qkv_bf, D3);
  attn_mfma<<<dim3(1024), 256, 0, stream>>>(qkv_bf, att_bf, ctr);
  gemm_8p<true><<<dim3(DD / 256, BT / 128), 512, 0, stream>>>(att_bf, wto, b_out, (void*)out, DD);
}

// Round 16
// 178.325 us; speedup vs baseline: 1.1087x; 1.1087x over previous
//
#include <hip/hip_runtime.h>
#include <hip/hip_bf16.h>

#define BB 4
#define TT 2048
#define DD 1024
#define HH 16
#define HDIM 64
#define BT (BB*TT)       // 8192
#define D3 (3*DD)        // 3072

typedef __attribute__((ext_vector_type(8))) short bf16x8;
typedef __attribute__((ext_vector_type(4))) float f32x4;

#if __has_builtin(__builtin_amdgcn_exp2f)
#define EXP2(x) __builtin_amdgcn_exp2f(x)
#else
#define EXP2(x) exp2f(x)
#endif

__device__ __forceinline__ ushort f2bf(float f) {
  union { float f; uint32_t u; } v; v.f = f;
  uint32_t u = v.u + 0x7FFFu + ((v.u >> 16) & 1u);
  return (ushort)(u >> 16);
}

__device__ __forceinline__ ushort f2bf_hw(float f) {
  __hip_bfloat16 h = __float2bfloat16(f);
  ushort u;
  __builtin_memcpy(&u, &h, 2);
  return u;
}

__device__ __forceinline__ float bf2f(ushort u) {
  union { uint32_t i; float f; } x; x.i = ((uint32_t)u) << 16; return x.f;
}

__device__ __forceinline__ void gload_lds16(const void* g, void* l) {
  __builtin_amdgcn_global_load_lds((const __attribute__((address_space(1))) void*)g,
                                   (__attribute__((address_space(3))) void*)l, 16, 0, 0);
}

// ---------------- fp32 -> bf16 convert (+ work-queue ctr zero) ----------------
__global__ __launch_bounds__(256)
void cvt_bf16(const float* __restrict__ in, ushort* __restrict__ out, int n4,
              uint* __restrict__ ctr) {
  if (blockIdx.x == 0 && threadIdx.x == 0) *ctr = 0u;
  int i = blockIdx.x * blockDim.x + threadIdx.x;
  int stride = gridDim.x * blockDim.x;
  for (; i < n4; i += stride) {
    float4 v = ((const float4*)in)[i];
    ushort4 o;
    o.x = f2bf(v.x); o.y = f2bf(v.y); o.z = f2bf(v.z); o.w = f2bf(v.w);
    ((ushort4*)out)[i] = o;
  }
}

// ---------------- fused weight transposes: fp32 [K][N] -> bf16 [N][K] ----------------
// blocks 0..(48*16-1): W_qkv (N=3072); rest: W_out (N=1024). Body identical to
// the proven transpose_cvt; only the base/N select differs (wave-uniform).
__global__ __launch_bounds__(256)
void transpose_cvt2(const float* __restrict__ Wq, ushort* __restrict__ Wtq,
                    const float* __restrict__ Wo, ushort* __restrict__ Wto) {
  const int flat = blockIdx.x;
  const bool isQ = flat < 48 * 16;
  const int lx = isQ ? flat : flat - 48 * 16;
  const int N = isQ ? D3 : DD;
  const int nb = N / 64;
  const float* W = isQ ? Wq : Wo;
  ushort* Wt = isQ ? Wtq : Wto;
  const int n0 = (lx % nb) * 64;
  const int k0 = (lx / nb) * 64;

  __shared__ ushort Tt[64][68];
  const int tid = threadIdx.x;
  const int r = tid >> 4;
  const int c4 = (tid & 15) * 4;
  #pragma unroll
  for (int i = 0; i < 4; ++i) {
    int row = r + i * 16;   // k-local
    float4 v = *(const float4*)&W[(size_t)(k0 + row) * N + n0 + c4];
    Tt[c4 + 0][row] = f2bf(v.x);
    Tt[c4 + 1][row] = f2bf(v.y);
    Tt[c4 + 2][row] = f2bf(v.z);
    Tt[c4 + 3][row] = f2bf(v.w);
  }
  __syncthreads();
  #pragma unroll
  for (int i = 0; i < 4; ++i) {
    int row = r + i * 16;   // n-local
    ushort4 tv = *(const ushort4*)&Tt[row][c4];
    *(ushort4*)&Wt[(size_t)(n0 + row) * 1024 + k0 + c4] = tv;
  }
}

// ---------------- 128x256 phased bf16 GEMM (8-wave, dbuf LDS) ----------------
template<bool F32OUT>
__global__ __launch_bounds__(512, 2)
void gemm_8p(const ushort* __restrict__ A, const ushort* __restrict__ Bw,
             const float* __restrict__ bias, void* __restrict__ C, int N) {
  __shared__ __align__(16) short lds[2 * (128 + 256) * 64];   // 96 KB

  const int tid = threadIdx.x;
  const int w = tid >> 6;          // 0..7
  const int wm = w >> 2;           // 0..1
  const int wn = w & 3;            // 0..3
  const int lane = tid & 63;
  const int li = lane & 15, g = lane >> 4;
  const int swz = (li & 7) << 4;   // read-side XOR (16B slot spread)

  const int bm = blockIdx.y * 128;
  const int bn = blockIdx.x * 256;
  const ushort* Ag = A + (size_t)bm * 1024;
  const ushort* Bg = Bw + (size_t)bn * 1024;

  const int lrow8 = lane >> 3;           // 0..7 (row within 8-row wave slab)
  const int chsw = (lane & 7) ^ lrow8;   // source chunk pre-swizzle (rule 21)

  f32x4 acc[4][4] = {};

#define STAGE6(t, p) do { \
  const int kk_ = (t) * 64; \
  short* Ad_ = lds + (p) * 24576; \
  short* Bd_ = Ad_ + 8192; \
  _Pragma("unroll") \
  for (int h_ = 0; h_ < 2; ++h_) { \
    const int r_ = h_ * 64 + w * 8; \
    gload_lds16(Ag + (size_t)(r_ + lrow8) * 1024 + kk_ + chsw * 8, Ad_ + r_ * 64); \
  } \
  _Pragma("unroll") \
  for (int j_ = 0; j_ < 4; ++j_) { \
    const int r_ = j_ * 64 + w * 8; \
    gload_lds16(Bg + (size_t)(r_ + lrow8) * 1024 + kk_ + chsw * 8, Bd_ + r_ * 64); \
  } \
} while (0)

  STAGE6(0, 0);
  asm volatile("s_waitcnt vmcnt(0)" ::: "memory");
  __builtin_amdgcn_sched_barrier(0);
  __builtin_amdgcn_s_barrier();

  for (int s = 0; s < 16; ++s) {
    const int cur = s & 1;
    const char* Ab = (const char*)lds + cur * 49152;   // bytes
    const char* Bb = Ab + 16384;

    if (s + 1 < 16) STAGE6(s + 1, cur ^ 1);

    #pragma unroll
    for (int kh = 0; kh < 2; ++kh) {
      bf16x8 af[4], bf[4];
      #pragma unroll
      for (int mi = 0; mi < 4; ++mi)
        af[mi] = *(const bf16x8*)(Ab + (wm * 64 + mi * 16 + li) * 128 + ((kh * 64 + g * 16) ^ swz));
      #pragma unroll
      for (int ni = 0; ni < 4; ++ni)
        bf[ni] = *(const bf16x8*)(Bb + (wn * 64 + ni * 16 + li) * 128 + ((kh * 64 + g * 16) ^ swz));
      __builtin_amdgcn_s_setprio(1);
      #pragma unroll
      for (int mi = 0; mi < 4; ++mi)
        #pragma unroll
        for (int ni = 0; ni < 4; ++ni)
          acc[mi][ni] = __builtin_amdgcn_mfma_f32_16x16x32_bf16(af[mi], bf[ni], acc[mi][ni], 0, 0, 0);
      __builtin_amdgcn_s_setprio(0);
      if (kh == 0) __builtin_amdgcn_s_barrier();
    }
    // ---- K-step boundary: next tile's loads must be in LDS ----
    asm volatile("s_waitcnt vmcnt(0)" ::: "memory");
    __builtin_amdgcn_sched_barrier(0);
    __builtin_amdgcn_s_barrier();
  }
#undef STAGE6

  #pragma unroll
  for (int ni = 0; ni < 4; ++ni) {
    int col = bn + wn * 64 + ni * 16 + li;
    float bv = bias[col];
    #pragma unroll
    for (int mi = 0; mi < 4; ++mi) {
      int row = bm + wm * 64 + mi * 16 + g * 4;
      #pragma unroll
      for (int r = 0; r < 4; ++r) {
        float v = acc[mi][ni][r] + bv;
        if (F32OUT) ((float*)C)[(size_t)(row + r) * N + col] = v;
        else        ((ushort*)C)[(size_t)(row + r) * N + col] = f2bf_hw(v);
      }
    }
  }
}

// ---------------- MFMA flash attention (persistent blocks + work queue) ----------------
// R9/R13 exact proven structure (81.0-81.6us, passed twice): reg-staged K+V
// prefetch, single Ks buffer, swizzled LDS, fixed-reference softmax.
#define NITEMS 1024

__global__ __launch_bounds__(256)
void attn_mfma(const ushort* __restrict__ qkv, ushort* __restrict__ out,
               uint* __restrict__ ctr) {
  __shared__ __align__(16) short Ks[64 * 64];
  __shared__ __align__(16) short Vt[64 * 64];
  __shared__ __align__(16) short Pl[4 * 16 * 64];
  __shared__ int s_item;

  const int tid = threadIdx.x;
  const int w = tid >> 6;
  const int lane = tid & 63;
  const int li = lane & 15, g = lane >> 4;
  const int sw = (li & 7) << 4;     // XOR swizzle const for this lane's rows

  char* KsB = (char*)Ks;
  char* VtB = (char*)Vt;
  char* PlB = (char*)Pl + w * 2048;

  const int krow0 = tid >> 3;     // 0..31
  const int kc = tid & 7;
  const int d0 = (tid >> 5) * 8;
  const int kp = tid & 31;
  const int kswz = (kc * 16) ^ ((krow0 & 7) << 4);

  for (;;) {
    if (tid == 0) s_item = (int)atomicAdd(ctr, 1u);
    __syncthreads();
    const int item = s_item;
    if (item >= NITEMS) return;

    const int qt = 15 - (item >> 6);   // longest first
    const int bh = item & 63;
    const int h = bh & 15, b = bh >> 4;
    const int qg0 = qt * 128 + w * 32;

    // Q frags, scaled by 1/sqrt(64) * log2(e)
    bf16x8 qfr[2][2];
    #pragma unroll
    for (int qf = 0; qf < 2; ++qf) {
      const ushort* qrow = qkv + (size_t)(b * TT + qg0 + qf * 16 + li) * D3 + h * HDIM;
      #pragma unroll
      for (int c = 0; c < 2; ++c) {
        uint4 raw = *(const uint4*)(qrow + c * 32 + g * 8);
        const ushort* rp = (const ushort*)&raw;
        bf16x8 v;
        #pragma unroll
        for (int j = 0; j < 8; ++j)
          v[j] = (short)f2bf_hw(bf2f(rp[j]) * 0.18033688f);
        qfr[qf][c] = v;
      }
    }

    f32x4 o[4][2] = {};
    float lsum[2] = {0.f, 0.f};

    const ushort* kbase = qkv + (size_t)b * TT * D3 + DD + h * HDIM;
    const ushort* vbase = kbase + DD;

    const int nt = 2 * qt + 2;
    const int itlast = 2 * qt + (w >> 1);

    uint4 kpre0, kpre1, vpre0, vpre1;
    {
      const ushort* kg = kbase + (size_t)krow0 * D3 + kc * 8;
      kpre0 = *(const uint4*)kg;
      kpre1 = *(const uint4*)(kg + (size_t)32 * D3);
      const ushort* vg = vbase + (size_t)(2 * kp) * D3 + d0;
      vpre0 = *(const uint4*)vg;
      vpre1 = *(const uint4*)(vg + D3);
    }

    for (int it = 0; it < nt; ++it) {
      const int k0 = it * 64;
      // commit prefetched tile to LDS (swizzled rows)
      *(uint4*)(KsB + krow0 * 128 + kswz) = kpre0;
      *(uint4*)(KsB + (krow0 + 32) * 128 + kswz) = kpre1;
      {
        const ushort* pa = (const ushort*)&vpre0;
        const ushort* pb = (const ushort*)&vpre1;
        #pragma unroll
        for (int j = 0; j < 8; ++j) {
          uint32_t pk = (uint32_t)pa[j] | ((uint32_t)pb[j] << 16);
          *(uint32_t*)(VtB + (d0 + j) * 128 + ((4 * kp) ^ (j << 4))) = pk;
        }
      }
      __syncthreads();
      // prefetch next tile (overlaps compute)
      if (it + 1 < nt) {
        const ushort* kg = kbase + (size_t)(k0 + 64 + krow0) * D3 + kc * 8;
        kpre0 = *(const uint4*)kg;
        kpre1 = *(const uint4*)(kg + (size_t)32 * D3);
        const ushort* vg = vbase + (size_t)(k0 + 64 + 2 * kp) * D3 + d0;
        vpre0 = *(const uint4*)vg;
        vpre1 = *(const uint4*)(vg + D3);
      }
      if (it <= itlast) {
        const bool domask = (it == itlast);
        bf16x8 pf[2][2];
        f32x4 s[2][4];
        // QK^T: K frags loaded once, used by both q-frags
        __builtin_amdgcn_s_setprio(1);
        #pragma unroll
        for (int kt = 0; kt < 4; ++kt) {
          const int row = kt * 16 + li;
          bf16x8 kf0 = *(bf16x8*)(KsB + row * 128 + ((g * 16) ^ sw));
          bf16x8 kf1 = *(bf16x8*)(KsB + row * 128 + ((64 + g * 16) ^ sw));
          #pragma unroll
          for (int qf = 0; qf < 2; ++qf) {
            f32x4 a = {0.f, 0.f, 0.f, 0.f};
            a = __builtin_amdgcn_mfma_f32_16x16x32_bf16(kf0, qfr[qf][0], a, 0, 0, 0);
            a = __builtin_amdgcn_mfma_f32_16x16x32_bf16(kf1, qfr[qf][1], a, 0, 0, 0);
            s[qf][kt] = a;
          }
        }
        __builtin_amdgcn_s_setprio(0);
        // softmax numerator: P = exp2(s) directly (|s| < ~12 in log2 domain)
        #pragma unroll
        for (int qf = 0; qf < 2; ++qf) {
          const int qrow = qg0 + qf * 16 + li;
          if (domask) {
            #pragma unroll
            for (int kt = 0; kt < 4; ++kt)
              #pragma unroll
              for (int r = 0; r < 4; ++r) {
                int key = k0 + kt * 16 + g * 4 + r;
                if (key > qrow) s[qf][kt][r] = -1e30f;
              }
          }
          float ls = 0.f;
          #pragma unroll
          for (int kt = 0; kt < 4; ++kt) {
            float p0 = EXP2(s[qf][kt][0]);
            float p1 = EXP2(s[qf][kt][1]);
            float p2 = EXP2(s[qf][kt][2]);
            float p3 = EXP2(s[qf][kt][3]);
            ls += (p0 + p1) + (p2 + p3);
            uint2 val;
            val.x = (uint32_t)f2bf_hw(p0) | ((uint32_t)f2bf_hw(p1) << 16);
            val.y = (uint32_t)f2bf_hw(p2) | ((uint32_t)f2bf_hw(p3) << 16);
            *(uint2*)(PlB + li * 128 + ((kt * 32 + g * 8) ^ sw)) = val;
          }
          lsum[qf] += ls;
          pf[qf][0] = *(bf16x8*)(PlB + li * 128 + ((g * 16) ^ sw));
          pf[qf][1] = *(bf16x8*)(PlB + li * 128 + ((64 + g * 16) ^ sw));
        }
        __builtin_amdgcn_s_setprio(1);
        #pragma unroll
        for (int dt = 0; dt < 4; ++dt) {
          const int vrow = dt * 16 + li;
          bf16x8 vf0 = *(bf16x8*)(VtB + vrow * 128 + ((g * 16) ^ sw));
          bf16x8 vf1 = *(bf16x8*)(VtB + vrow * 128 + ((64 + g * 16) ^ sw));
          #pragma unroll
          for (int qf = 0; qf < 2; ++qf) {
            o[dt][qf] = __builtin_amdgcn_mfma_f32_16x16x32_bf16(vf0, pf[qf][0], o[dt][qf], 0, 0, 0);
            o[dt][qf] = __builtin_amdgcn_mfma_f32_16x16x32_bf16(vf1, pf[qf][1], o[dt][qf], 0, 0, 0);
          }
        }
        __builtin_amdgcn_s_setprio(0);
      }
      __syncthreads();
    }

    #pragma unroll
    for (int qf = 0; qf < 2; ++qf) {
      float lt = lsum[qf];
      lt += __shfl_xor(lt, 16);
      lt += __shfl_xor(lt, 32);
      float inv = 1.f / lt;
      ushort* orow = out + (size_t)(b * TT + qg0 + qf * 16 + li) * DD + h * HDIM;
      #pragma unroll
      for (int dt = 0; dt < 4; ++dt) {
        uint2 pk;
        pk.x = (uint32_t)f2bf_hw(o[dt][qf][0] * inv) | ((uint32_t)f2bf_hw(o[dt][qf][1] * inv) << 16);
        pk.y = (uint32_t)f2bf_hw(o[dt][qf][2] * inv) | ((uint32_t)f2bf_hw(o[dt][qf][3] * inv) << 16);
        *(uint2*)&orow[dt * 16 + g * 4] = pk;
      }
    }
  }
}

extern "C" void kernel_launch(void* const* d_in, const int* in_sizes, int n_in,
                              void* d_out, int out_size, void* d_ws, size_t ws_size,
                              hipStream_t stream) {
  const float* x     = (const float*)d_in[0];
  const float* W_qkv = (const float*)d_in[1];
  const float* b_qkv = (const float*)d_in[2];
  const float* W_out = (const float*)d_in[3];
  const float* b_out = (const float*)d_in[4];
  float* out = (float*)d_out;

  ushort* x_bf   = (ushort*)d_ws;                   // 8192*1024
  ushort* wtq    = x_bf + (size_t)BT * DD;          // 3072*1024
  ushort* wto    = wtq + (size_t)D3 * DD;           // 1024*1024
  ushort* qkv_bf = wto + (size_t)DD * DD;           // 8192*3072
  ushort* att_bf = qkv_bf + (size_t)BT * D3;        // 8192*1024
  uint*   ctr    = (uint*)(att_bf + (size_t)BT * DD);

  cvt_bf16<<<2048, 256, 0, stream>>>(x, x_bf, BT * DD / 4, ctr);
  transpose_cvt2<<<dim3(48 * 16 + 16 * 16), 256, 0, stream>>>(W_qkv, wtq, W_out, wto);

  gemm_8p<false><<<dim3(D3 / 256, BT / 128), 512, 0, stream>>>(x_bf, wtq, b_qkv, (void*)qkv_bf, D3);
  attn_mfma<<<dim3(1024), 256, 0, stream>>>(qkv_bf, att_bf, ctr);
  gemm_8p<true><<<dim3(DD / 256, BT / 128), 512, 0, stream>>>(att_bf, wto, b_out, (void*)out, DD);
}